// Round 2
// baseline (290.541 us; speedup 1.0000x reference)
//
#include <hip/hip_runtime.h>

#define EPS 1e-6f
#define LL 4096
#define HE 512

typedef __attribute__((ext_vector_type(8))) short short8;
typedef __attribute__((ext_vector_type(4))) float f32x4;

__device__ __forceinline__ unsigned short f2bf(float f) {
    union { float f; unsigned u; } v; v.f = f;
    unsigned r = v.u + 0x7FFFu + ((v.u >> 16) & 1u);  // RNE
    return (unsigned short)(r >> 16);
}
__device__ __forceinline__ float bf2f(unsigned short s) {
    union { unsigned u; float f; } v; v.u = ((unsigned)s) << 16;
    return v.f;
}
// async global->LDS, 16B per lane; LDS dest = wave-uniform base + lane*16
__device__ __forceinline__ void gl16(const unsigned short* g, unsigned short* l) {
    __builtin_amdgcn_global_load_lds(
        (const __attribute__((address_space(1))) unsigned int*)(const void*)g,
        (__attribute__((address_space(3))) unsigned int*)(void*)l,
        16, 0, 0);
}

// ---- k1: read q once -> Vt (bf16 [n][l], local-b), Vb (bf16 [l][n], local-b),
//          sumV/sumsq atomics (global-b) ----------------------------------
__global__ __launch_bounds__(256) void k1_fused(const float* __restrict__ q,
        unsigned short* __restrict__ Vt, unsigned short* __restrict__ Vb,
        float* __restrict__ sumV, float* __restrict__ sumsq, int bofs) {
    __shared__ __attribute__((aligned(16))) unsigned short lds[64][68];
    int blk = blockIdx.x;
    int b = blk >> 9, lt = (blk >> 3) & 63, nt = blk & 7;
    int gb = bofs + b;
    int t = threadIdx.x;
    int row = t >> 4, col = (t & 15) << 2;
    const float* base = q + ((size_t)gb * LL + lt * 64) * HE + nt * 64;
    unsigned short* vbb = Vb + ((size_t)b * LL + lt * 64) * HE + nt * 64;
    #pragma unroll
    for (int i = 0; i < 4; i++) {
        int l = row + i * 16;
        float4 v = *(const float4*)(base + (size_t)l * HE + col);
        ushort4 w;
        w.x = f2bf(v.x); w.y = f2bf(v.y); w.z = f2bf(v.z); w.w = f2bf(v.w);
        lds[col+0][l] = w.x; lds[col+1][l] = w.y;
        lds[col+2][l] = w.z; lds[col+3][l] = w.w;
        *(ushort4*)(vbb + (size_t)l * HE + col) = w;
    }
    __syncthreads();
    unsigned short* ob = Vt + ((size_t)b * HE + nt * 64) * LL + lt * 64;
    #pragma unroll
    for (int i = 0; i < 4; i++) {
        int n = row + i * 16;
        ushort4 w;
        w.x = lds[n][col+0]; w.y = lds[n][col+1];
        w.z = lds[n][col+2]; w.w = lds[n][col+3];
        *(ushort4*)(ob + (size_t)n * LL + col) = w;
        float x0 = bf2f(w.x), x1 = bf2f(w.y), x2 = bf2f(w.z), x3 = bf2f(w.w);
        float s = x0 + x1 + x2 + x3;
        float qq = x0*x0 + x1*x1 + x2*x2 + x3*x3;
        s += __shfl_xor(s, 1);  qq += __shfl_xor(qq, 1);
        s += __shfl_xor(s, 2);  qq += __shfl_xor(qq, 2);
        s += __shfl_xor(s, 4);  qq += __shfl_xor(qq, 4);
        s += __shfl_xor(s, 8);  qq += __shfl_xor(qq, 8);
        if ((t & 15) == 0) {
            atomicAdd(&sumV[gb * HE + nt * 64 + n], s);
            atomicAdd(&sumsq[gb * HE + nt * 64 + n], qq);
        }
    }
}

// ---- k2: cvec = (sumV*inv + eps)*inv ; invn = rsqrt(sumsq) --------------
__global__ __launch_bounds__(256) void k2_finalize(const float* __restrict__ sumV,
        const float* __restrict__ sumsq, float* __restrict__ cvec,
        float* __restrict__ invn, int bofs) {
    int i = bofs * HE + blockIdx.x * 256 + threadIdx.x;
    float sv = sumV[i];
    float inv = 1.0f / sqrtf(sumsq[i]);
    invn[i] = inv;
    cvec[i] = (sv * inv + EPS) * inv;
}

// ---- k3: dvec[b,l] = sum_n Vb[l,n]*cvec[n]  (GEMV) ----------------------
__global__ __launch_bounds__(256) void k3_dvec(const unsigned short* __restrict__ Vb,
        const float* __restrict__ cvec, float* __restrict__ dvec, int bofs) {
    int blk = blockIdx.x;
    int b = blk >> 7, lblk = blk & 127;
    int t = threadIdx.x;
    int lloc = t >> 3, j = t & 7;
    int l = lblk * 32 + lloc;
    const unsigned short* rowp = Vb + ((size_t)b * LL + l) * HE + j * 64;
    const float* cp = cvec + (bofs + b) * HE + j * 64;
    float d = 0.f;
    #pragma unroll
    for (int g = 0; g < 8; g++) {
        short8 v = *(const short8*)(rowp + g * 8);
        float4 c0 = *(const float4*)(cp + g * 8);
        float4 c1 = *(const float4*)(cp + g * 8 + 4);
        d += bf2f((unsigned short)v[0]) * c0.x + bf2f((unsigned short)v[1]) * c0.y
           + bf2f((unsigned short)v[2]) * c0.z + bf2f((unsigned short)v[3]) * c0.w
           + bf2f((unsigned short)v[4]) * c1.x + bf2f((unsigned short)v[5]) * c1.y
           + bf2f((unsigned short)v[6]) * c1.z + bf2f((unsigned short)v[7]) * c1.w;
    }
    d += __shfl_xor(d, 1); d += __shfl_xor(d, 2); d += __shfl_xor(d, 4);
    if (j == 0) dvec[(size_t)(bofs + b) * LL + l] = d;
}

// ---- k4: Gram partials, split-K=8, symmetric pairs, swizzled LDS --------
__global__ __launch_bounds__(256) void k4_gram(const unsigned short* __restrict__ Vt,
        float* __restrict__ Gp) {
    __shared__ __attribute__((aligned(16))) unsigned short la[128][64];
    __shared__ __attribute__((aligned(16))) unsigned short lb[128][64];
    int blk = blockIdx.x;
    int b = blk / 80;
    int rem = blk - b * 80;
    int pair = rem >> 3, split = rem & 7;
    int nt = (pair < 4) ? 0 : (pair < 7) ? 1 : (pair < 9) ? 2 : 3;
    int off = (nt * (9 - nt)) >> 1;
    int mt = nt + pair - off;
    int N0 = nt * 128, M0 = mt * 128;
    int t = threadIdx.x;
    int w = t >> 6, lane = t & 63;
    int wr = w >> 1, wc = w & 1;
    int rl = lane >> 3;                    // row-in-8 for staging
    int cl = ((lane & 7) ^ rl) << 3;       // pre-swizzled source chunk (elems)
    int lr = lane & 15, q4 = lane >> 4;
    int ch0 = (q4 ^ (lane & 7)) << 3;      // swizzled read col, ks=0 (elems)
    const unsigned short* pa = Vt + ((size_t)b * HE + N0) * LL + split * 512;
    const unsigned short* pb = Vt + ((size_t)b * HE + M0) * LL + split * 512;
    f32x4 acc[4][4] = {};
    for (int kb = 0; kb < 8; kb++) {
        int k0 = kb * 64;
        #pragma unroll
        for (int p = 0; p < 4; p++) {
            int r0 = p * 32 + w * 8;
            gl16(pa + (size_t)(r0 + rl) * LL + k0 + cl, &la[r0][0]);
            gl16(pb + (size_t)(r0 + rl) * LL + k0 + cl, &lb[r0][0]);
        }
        __syncthreads();
        #pragma unroll
        for (int ks = 0; ks < 2; ks++) {
            int colA = ch0 ^ (ks << 5);
            short8 af[4], bfr[4];
            #pragma unroll
            for (int i = 0; i < 4; i++)
                af[i] = *(const short8*)&la[wr*64 + i*16 + lr][colA];
            #pragma unroll
            for (int j = 0; j < 4; j++)
                bfr[j] = *(const short8*)&lb[wc*64 + j*16 + lr][colA];
            #pragma unroll
            for (int i = 0; i < 4; i++)
                #pragma unroll
                for (int j = 0; j < 4; j++)
                    acc[i][j] = __builtin_amdgcn_mfma_f32_16x16x32_bf16(af[i], bfr[j], acc[i][j], 0, 0, 0);
        }
        __syncthreads();
    }
    size_t tbase = ((size_t)(b * 10 + pair) * 8 + split) * 16384;
    #pragma unroll
    for (int i = 0; i < 4; i++) {
        int nb = wr*64 + i*16 + q4*4;
        #pragma unroll
        for (int j = 0; j < 4; j++) {
            int ml = wc*64 + j*16 + lr;
            #pragma unroll
            for (int jj = 0; jj < 4; jj++)
                Gp[tbase + (size_t)(nb + jj) * 128 + ml] = acc[i][j][jj];
        }
    }
}

// ---- k5: sum splits, scale by invn outer, write KQb + mirror ------------
__global__ __launch_bounds__(256) void k5_reduce(const float* __restrict__ Gp,
        const float* __restrict__ invn, unsigned short* __restrict__ KQb, int bofs) {
    __shared__ unsigned short lds_t[128][130];
    int blk = blockIdx.x;
    int b = blk / 10, pair = blk % 10;
    int nt = (pair < 4) ? 0 : (pair < 7) ? 1 : (pair < 9) ? 2 : 3;
    int off = (nt * (9 - nt)) >> 1;
    int mt = nt + pair - off;
    int N0 = nt * 128, M0 = mt * 128;
    int t = threadIdx.x;
    const float* gp = Gp + ((size_t)(b * 10 + pair) * 8) * 16384;
    const float* inb = invn + (size_t)(bofs + b) * HE;
    #pragma unroll 4
    for (int e = 0; e < 64; e++) {
        int idx = e * 256 + t;
        int nl = idx >> 7, ml = idx & 127;
        float s = 0.f;
        #pragma unroll
        for (int sp = 0; sp < 8; sp++) s += gp[(size_t)sp * 16384 + idx];
        unsigned short v = f2bf(s * inb[N0 + nl] * inb[M0 + ml]);
        lds_t[nl][ml] = v;
        KQb[((size_t)b * HE + N0 + nl) * HE + M0 + ml] = v;
    }
    __syncthreads();
    #pragma unroll 4
    for (int e = 0; e < 64; e++) {
        int idx = e * 256 + t;
        int ml = idx >> 7, nl = idx & 127;
        KQb[((size_t)b * HE + M0 + ml) * HE + N0 + nl] = lds_t[nl][ml];
    }
}

// ---- k6: part GEMM (KQb x Vb) + tailor/sumV/residual epilogue -----------
__global__ __launch_bounds__(256) void k6_part(const unsigned short* __restrict__ KQb,
        const unsigned short* __restrict__ Vb, const float* __restrict__ dvec,
        const float* __restrict__ sumV, const float* __restrict__ gamma,
        float* __restrict__ out, int bofs) {
    __shared__ __attribute__((aligned(16))) unsigned short la[128][64];
    __shared__ __attribute__((aligned(16))) unsigned short lb[128][64];
    int blk = blockIdx.x;
    int b = blk >> 7, mt = (blk >> 5) & 3, lt = blk & 31;
    int gb = bofs + b;
    int M0 = mt * 128, L0 = lt * 128;
    int t = threadIdx.x;
    int w = t >> 6, lane = t & 63;
    int wr = w >> 1, wc = w & 1;
    int rl = lane >> 3;
    int cl = ((lane & 7) ^ rl) << 3;
    int lr = lane & 15, q4 = lane >> 4;
    int ch0 = (q4 ^ (lane & 7)) << 3;
    const unsigned short* pa = KQb + ((size_t)b * HE + M0) * HE;
    const unsigned short* pb = Vb + ((size_t)b * LL + L0) * HE;
    f32x4 acc[4][4] = {};
    for (int kb = 0; kb < 8; kb++) {
        int k0 = kb * 64;
        #pragma unroll
        for (int p = 0; p < 4; p++) {
            int r0 = p * 32 + w * 8;
            gl16(pa + (size_t)(r0 + rl) * HE + k0 + cl, &la[r0][0]);
            gl16(pb + (size_t)(r0 + rl) * HE + k0 + cl, &lb[r0][0]);
        }
        __syncthreads();
        #pragma unroll
        for (int ks = 0; ks < 2; ks++) {
            int colA = ch0 ^ (ks << 5);
            short8 af[4], bfr[4];
            #pragma unroll
            for (int i = 0; i < 4; i++)
                af[i] = *(const short8*)&la[wr*64 + i*16 + lr][colA];
            #pragma unroll
            for (int j = 0; j < 4; j++)
                bfr[j] = *(const short8*)&lb[wc*64 + j*16 + lr][colA];
            #pragma unroll
            for (int i = 0; i < 4; i++)
                #pragma unroll
                for (int j = 0; j < 4; j++)
                    acc[i][j] = __builtin_amdgcn_mfma_f32_16x16x32_bf16(af[i], bfr[j], acc[i][j], 0, 0, 0);
        }
        __syncthreads();
    }
    float gma = gamma[0];
    #pragma unroll
    for (int j = 0; j < 4; j++) {
        int lglob = L0 + wc*64 + j*16 + lr;
        float dt = dvec[(size_t)gb * LL + lglob];
        float tailor = 1.0f / (512.0f + dt);
        #pragma unroll
        for (int i = 0; i < 4; i++) {
            int m4 = M0 + wr*64 + i*16 + q4*4;
            size_t ofs = ((size_t)gb * LL + lglob) * HE + m4;
            ushort4 rv = *(const ushort4*)(Vb + ((size_t)b * LL + lglob) * HE + m4);
            float4 vs = *(const float4*)(sumV + (size_t)gb * HE + m4);
            float4 o;
            o.x = bf2f(rv.x) + gma * (vs.x + acc[i][j][0]) * tailor;
            o.y = bf2f(rv.y) + gma * (vs.y + acc[i][j][1]) * tailor;
            o.z = bf2f(rv.z) + gma * (vs.z + acc[i][j][2]) * tailor;
            o.w = bf2f(rv.w) + gma * (vs.w + acc[i][j][3]) * tailor;
            *(float4*)(out + ofs) = o;
        }
    }
}

extern "C" void kernel_launch(void* const* d_in, const int* in_sizes, int n_in,
                              void* d_out, int out_size, void* d_ws, size_t ws_size,
                              hipStream_t stream) {
    const float* q     = (const float*)d_in[0];
    const float* gamma = (const float*)d_in[4];
    float* out = (float*)d_out;
    char* ws = (char*)d_ws;
    // ws layout (68.5 MiB total; Vt/Vb/KQb are per-half, local-b indexed)
    float* sumV  = (float*)(ws);                     // 32 KiB (16 batches)
    float* sumsq = (float*)(ws + 32768);             // 32 KiB
    float* cvec  = (float*)(ws + 65536);             // 32 KiB
    float* invn  = (float*)(ws + 98304);             // 32 KiB
    float* dvec  = (float*)(ws + 131072);            // 256 KiB (16 batches)
    unsigned short* KQb = (unsigned short*)(ws + 524288);               // 4 MiB
    unsigned short* Vt  = (unsigned short*)(ws + 524288 + 4194304);     // 32 MiB
    unsigned short* Vb  = (unsigned short*)(ws + 524288 + 4194304 + 33554432); // 32 MiB
    // Gram partials in upper half of d_out (40 MiB), consumed before k6 writes
    float* Gp = (float*)d_out + 16777216;

    hipMemsetAsync(ws, 0, 65536, stream);  // zero sumV/sumsq
    for (int h = 0; h < 2; h++) {
        int bofs = h * 8;
        k1_fused  <<<4096, 256, 0, stream>>>(q, Vt, Vb, sumV, sumsq, bofs);
        k2_finalize<<<16,  256, 0, stream>>>(sumV, sumsq, cvec, invn, bofs);
        k3_dvec   <<<1024, 256, 0, stream>>>(Vb, cvec, dvec, bofs);
        k4_gram   <<<640,  256, 0, stream>>>(Vt, Gp);
        k5_reduce <<<80,   256, 0, stream>>>(Gp, invn, KQb, bofs);
        k6_part   <<<1024, 256, 0, stream>>>(KQb, Vb, dvec, sumV, gamma, out, bofs);
    }
}

// Round 3
// 235.226 us; speedup vs baseline: 1.2352x; 1.2352x over previous
//
#include <hip/hip_runtime.h>

#define EPS 1e-6f
#define LL 4096
#define HE 512

typedef __attribute__((ext_vector_type(8))) short short8;
typedef __attribute__((ext_vector_type(4))) float f32x4;

__device__ __forceinline__ unsigned short f2bf(float f) {
    union { float f; unsigned u; } v; v.f = f;
    unsigned r = v.u + 0x7FFFu + ((v.u >> 16) & 1u);  // RNE
    return (unsigned short)(r >> 16);
}
__device__ __forceinline__ float bf2f(unsigned short s) {
    union { unsigned u; float f; } v; v.u = ((unsigned)s) << 16;
    return v.f;
}
// async global->LDS, 16B per lane; LDS dest = wave-uniform base + lane*16
__device__ __forceinline__ void gl16(const unsigned short* g, unsigned short* l) {
    __builtin_amdgcn_global_load_lds(
        (const __attribute__((address_space(1))) unsigned int*)(const void*)g,
        (__attribute__((address_space(3))) unsigned int*)(void*)l,
        16, 0, 0);
}

// ---- k1: read q once -> Vt (bf16 [n][l]), Vb (bf16 [l][n]), stat partials ----
__global__ __launch_bounds__(256) void k1_fused(const float* __restrict__ q,
        unsigned short* __restrict__ Vt, unsigned short* __restrict__ Vb,
        float* __restrict__ ps, float* __restrict__ pq, int bofs) {
    __shared__ unsigned short lds[64][65];
    int blk = blockIdx.x;
    int b = blk >> 9, lt = (blk >> 3) & 63, nt = blk & 7;
    int gb = bofs + b;
    int t = threadIdx.x;
    int row = t >> 4, col = (t & 15) << 2;
    const float* base = q + ((size_t)gb * LL + lt * 64) * HE + nt * 64;
    unsigned short* vbb = Vb + ((size_t)b * LL + lt * 64) * HE + nt * 64;
    #pragma unroll
    for (int i = 0; i < 4; i++) {
        int l = row + i * 16;
        float4 v = *(const float4*)(base + (size_t)l * HE + col);
        ushort4 w;
        w.x = f2bf(v.x); w.y = f2bf(v.y); w.z = f2bf(v.z); w.w = f2bf(v.w);
        lds[col+0][l] = w.x; lds[col+1][l] = w.y;
        lds[col+2][l] = w.z; lds[col+3][l] = w.w;
        *(ushort4*)(vbb + (size_t)l * HE + col) = w;
    }
    __syncthreads();
    unsigned short* ob = Vt + ((size_t)b * HE + nt * 64) * LL + lt * 64;
    #pragma unroll
    for (int i = 0; i < 4; i++) {
        int n = row + i * 16;
        ushort4 w;
        w.x = lds[n][col+0]; w.y = lds[n][col+1];
        w.z = lds[n][col+2]; w.w = lds[n][col+3];
        *(ushort4*)(ob + (size_t)n * LL + col) = w;
        float x0 = bf2f(w.x), x1 = bf2f(w.y), x2 = bf2f(w.z), x3 = bf2f(w.w);
        float s = x0 + x1 + x2 + x3;
        float qq = x0*x0 + x1*x1 + x2*x2 + x3*x3;
        s += __shfl_xor(s, 1);  qq += __shfl_xor(qq, 1);
        s += __shfl_xor(s, 2);  qq += __shfl_xor(qq, 2);
        s += __shfl_xor(s, 4);  qq += __shfl_xor(qq, 4);
        s += __shfl_xor(s, 8);  qq += __shfl_xor(qq, 8);
        if ((t & 15) == 0) {
            int idx = lt * 4096 + b * 512 + nt * 64 + n;
            ps[idx] = s;
            pq[idx] = qq;
        }
    }
}

// ---- k2: reduce partials -> sumV, cvec, invn ----------------------------
__global__ __launch_bounds__(256) void k2_reduce(const float* __restrict__ ps,
        const float* __restrict__ pq, float* __restrict__ sumV,
        float* __restrict__ cvec, float* __restrict__ invn, int bofs) {
    int i = blockIdx.x * 256 + threadIdx.x;   // 0..4095 = b_local*512 + n
    float s = 0.f, qq = 0.f;
    #pragma unroll 8
    for (int lt = 0; lt < 64; lt++) {
        s  += ps[lt * 4096 + i];
        qq += pq[lt * 4096 + i];
    }
    int o = bofs * HE + i;
    float inv = 1.0f / sqrtf(qq);
    sumV[o] = s;
    invn[o] = inv;
    cvec[o] = (s * inv + EPS) * inv;
}

// ---- k3: dvec[b,l] = sum_n Vb[l,n]*cvec[n]  (GEMV) ----------------------
__global__ __launch_bounds__(256) void k3_dvec(const unsigned short* __restrict__ Vb,
        const float* __restrict__ cvec, float* __restrict__ dvec, int bofs) {
    int blk = blockIdx.x;
    int b = blk >> 7, lblk = blk & 127;
    int t = threadIdx.x;
    int lloc = t >> 3, j = t & 7;
    int l = lblk * 32 + lloc;
    const unsigned short* rowp = Vb + ((size_t)b * LL + l) * HE + j * 64;
    const float* cp = cvec + (bofs + b) * HE + j * 64;
    float d = 0.f;
    #pragma unroll
    for (int g = 0; g < 8; g++) {
        short8 v = *(const short8*)(rowp + g * 8);
        float4 c0 = *(const float4*)(cp + g * 8);
        float4 c1 = *(const float4*)(cp + g * 8 + 4);
        d += bf2f((unsigned short)v[0]) * c0.x + bf2f((unsigned short)v[1]) * c0.y
           + bf2f((unsigned short)v[2]) * c0.z + bf2f((unsigned short)v[3]) * c0.w
           + bf2f((unsigned short)v[4]) * c1.x + bf2f((unsigned short)v[5]) * c1.y
           + bf2f((unsigned short)v[6]) * c1.z + bf2f((unsigned short)v[7]) * c1.w;
    }
    d += __shfl_xor(d, 1); d += __shfl_xor(d, 2); d += __shfl_xor(d, 4);
    if (j == 0) dvec[(size_t)(bofs + b) * LL + l] = d;
}

// ---- k4: Gram partials (bf16, [ml][nl]), split-K=8, symmetric pairs -----
__global__ __launch_bounds__(256) void k4_gram(const unsigned short* __restrict__ Vt,
        unsigned short* __restrict__ Gp) {
    __shared__ __attribute__((aligned(16))) unsigned short la[128][64];
    __shared__ __attribute__((aligned(16))) unsigned short lb[128][64];
    int blk = (blockIdx.x & 7) * 80 + (blockIdx.x >> 3);  // XCD swizzle (640 = 8*80)
    int b = blk / 80;
    int rem = blk - b * 80;
    int pair = rem >> 3, split = rem & 7;
    int nt = (pair < 4) ? 0 : (pair < 7) ? 1 : (pair < 9) ? 2 : 3;
    int off = (nt * (9 - nt)) >> 1;
    int mt = nt + pair - off;
    bool diag = (nt == mt);
    int N0 = nt * 128, M0 = mt * 128;
    int t = threadIdx.x;
    int w = t >> 6, lane = t & 63;
    int wr = w >> 1, wc = w & 1;
    int rl = lane >> 3;                    // row-in-8 for staging
    int cl = ((lane & 7) ^ rl) << 3;       // pre-swizzled source chunk (elems)
    int lr = lane & 15, q4 = lane >> 4;
    int ch0 = (q4 ^ (lane & 7)) << 3;      // swizzled read col, ks=0 (elems)
    const unsigned short* pa = Vt + ((size_t)b * HE + N0) * LL + split * 512;
    const unsigned short* pb = Vt + ((size_t)b * HE + M0) * LL + split * 512;
    const unsigned short (*LB)[64] = diag ? la : lb;
    f32x4 acc[4][4] = {};
    for (int kb = 0; kb < 8; kb++) {
        int k0 = kb * 64;
        #pragma unroll
        for (int p = 0; p < 4; p++) {
            int r0 = p * 32 + w * 8;
            gl16(pa + (size_t)(r0 + rl) * LL + k0 + cl, &la[r0][0]);
            if (!diag) gl16(pb + (size_t)(r0 + rl) * LL + k0 + cl, &lb[r0][0]);
        }
        __syncthreads();
        #pragma unroll
        for (int ks = 0; ks < 2; ks++) {
            int colA = ch0 ^ (ks << 5);
            short8 af[4], bfr[4];
            #pragma unroll
            for (int i = 0; i < 4; i++)
                af[i] = *(const short8*)&la[wr*64 + i*16 + lr][colA];
            #pragma unroll
            for (int j = 0; j < 4; j++)
                bfr[j] = *(const short8*)&LB[wc*64 + j*16 + lr][colA];
            #pragma unroll
            for (int i = 0; i < 4; i++)
                #pragma unroll
                for (int j = 0; j < 4; j++)
                    acc[i][j] = __builtin_amdgcn_mfma_f32_16x16x32_bf16(af[i], bfr[j], acc[i][j], 0, 0, 0);
        }
        __syncthreads();
    }
    // store bf16 partials, layout [ml*128 + nl] -> ushort4 along n
    size_t tbase = ((size_t)(b * 10 + pair) * 8 + split) * 16384;
    #pragma unroll
    for (int i = 0; i < 4; i++) {
        int nb = wr*64 + i*16 + q4*4;
        #pragma unroll
        for (int j = 0; j < 4; j++) {
            int ml = wc*64 + j*16 + lr;
            ushort4 wv;
            wv.x = f2bf(acc[i][j][0]); wv.y = f2bf(acc[i][j][1]);
            wv.z = f2bf(acc[i][j][2]); wv.w = f2bf(acc[i][j][3]);
            *(ushort4*)&Gp[tbase + (size_t)ml * 128 + nb] = wv;
        }
    }
}

// ---- k5: sum splits, scale by invn outer, write KQb both orientations ---
__global__ __launch_bounds__(256) void k5_reduce(const unsigned short* __restrict__ Gp,
        const float* __restrict__ invn, unsigned short* __restrict__ KQb, int bofs) {
    __shared__ unsigned short lds_t[128][130];
    int blk = blockIdx.x;
    int b = blk / 10, pair = blk % 10;
    int nt = (pair < 4) ? 0 : (pair < 7) ? 1 : (pair < 9) ? 2 : 3;
    int off = (nt * (9 - nt)) >> 1;
    int mt = nt + pair - off;
    int N0 = nt * 128, M0 = mt * 128;
    int t = threadIdx.x;
    const unsigned short* gp = Gp + ((size_t)(b * 10 + pair) * 8) * 16384;
    const float* inb = invn + (size_t)(bofs + b) * HE;
    #pragma unroll 2
    for (int e = 0; e < 32; e++) {
        int idx = e * 512 + t * 2;           // [ml][nl] pairs
        int ml = idx >> 7, nl = idx & 127;
        float s0 = 0.f, s1 = 0.f;
        #pragma unroll
        for (int sp = 0; sp < 8; sp++) {
            unsigned g2 = *(const unsigned*)&gp[(size_t)sp * 16384 + idx];
            s0 += bf2f((unsigned short)(g2 & 0xFFFF));
            s1 += bf2f((unsigned short)(g2 >> 16));
        }
        float im = inb[M0 + ml];
        ushort2 v;
        v.x = f2bf(s0 * inb[N0 + nl] * im);
        v.y = f2bf(s1 * inb[N0 + nl + 1] * im);
        *(ushort2*)&KQb[((size_t)b * HE + M0 + ml) * HE + N0 + nl] = v;
        *(ushort2*)&lds_t[ml][nl] = v;
    }
    __syncthreads();
    #pragma unroll 2
    for (int e = 0; e < 32; e++) {
        int idx = e * 512 + t * 2;
        int nl = idx >> 7, ml = idx & 127;   // transposed roles
        ushort2 v;
        v.x = lds_t[ml][nl];
        v.y = lds_t[ml + 1][nl];
        *(ushort2*)&KQb[((size_t)b * HE + N0 + nl) * HE + M0 + ml] = v;
    }
}

// ---- k6: part GEMM (KQb x Vb) + tailor/sumV/residual epilogue -----------
__global__ __launch_bounds__(256) void k6_part(const unsigned short* __restrict__ KQb,
        const unsigned short* __restrict__ Vb, const float* __restrict__ dvec,
        const float* __restrict__ sumV, const float* __restrict__ gamma,
        float* __restrict__ out, int bofs) {
    __shared__ __attribute__((aligned(16))) unsigned short la[128][64];
    __shared__ __attribute__((aligned(16))) unsigned short lb[128][64];
    int blk = (blockIdx.x & 7) * 128 + (blockIdx.x >> 3);  // XCD swizzle (1024 = 8*128)
    int b = blk >> 7, mt = (blk >> 5) & 3, lt = blk & 31;
    int gb = bofs + b;
    int M0 = mt * 128, L0 = lt * 128;
    int t = threadIdx.x;
    int w = t >> 6, lane = t & 63;
    int wr = w >> 1, wc = w & 1;
    int rl = lane >> 3;
    int cl = ((lane & 7) ^ rl) << 3;
    int lr = lane & 15, q4 = lane >> 4;
    int ch0 = (q4 ^ (lane & 7)) << 3;
    const unsigned short* pa = KQb + ((size_t)b * HE + M0) * HE;
    const unsigned short* pb = Vb + ((size_t)b * LL + L0) * HE;
    f32x4 acc[4][4] = {};
    for (int kb = 0; kb < 8; kb++) {
        int k0 = kb * 64;
        #pragma unroll
        for (int p = 0; p < 4; p++) {
            int r0 = p * 32 + w * 8;
            gl16(pa + (size_t)(r0 + rl) * HE + k0 + cl, &la[r0][0]);
            gl16(pb + (size_t)(r0 + rl) * HE + k0 + cl, &lb[r0][0]);
        }
        __syncthreads();
        #pragma unroll
        for (int ks = 0; ks < 2; ks++) {
            int colA = ch0 ^ (ks << 5);
            short8 af[4], bfr[4];
            #pragma unroll
            for (int i = 0; i < 4; i++)
                af[i] = *(const short8*)&la[wr*64 + i*16 + lr][colA];
            #pragma unroll
            for (int j = 0; j < 4; j++)
                bfr[j] = *(const short8*)&lb[wc*64 + j*16 + lr][colA];
            #pragma unroll
            for (int i = 0; i < 4; i++)
                #pragma unroll
                for (int j = 0; j < 4; j++)
                    acc[i][j] = __builtin_amdgcn_mfma_f32_16x16x32_bf16(af[i], bfr[j], acc[i][j], 0, 0, 0);
        }
        __syncthreads();
    }
    float gma = gamma[0];
    #pragma unroll
    for (int j = 0; j < 4; j++) {
        int lglob = L0 + wc*64 + j*16 + lr;
        float dt = dvec[(size_t)gb * LL + lglob];
        float tailor = 1.0f / (512.0f + dt);
        #pragma unroll
        for (int i = 0; i < 4; i++) {
            int m4 = M0 + wr*64 + i*16 + q4*4;
            size_t ofs = ((size_t)gb * LL + lglob) * HE + m4;
            ushort4 rv = *(const ushort4*)(Vb + ((size_t)b * LL + lglob) * HE + m4);
            float4 vs = *(const float4*)(sumV + (size_t)gb * HE + m4);
            float4 o;
            o.x = bf2f(rv.x) + gma * (vs.x + acc[i][j][0]) * tailor;
            o.y = bf2f(rv.y) + gma * (vs.y + acc[i][j][1]) * tailor;
            o.z = bf2f(rv.z) + gma * (vs.z + acc[i][j][2]) * tailor;
            o.w = bf2f(rv.w) + gma * (vs.w + acc[i][j][3]) * tailor;
            *(float4*)(out + ofs) = o;
        }
    }
}

extern "C" void kernel_launch(void* const* d_in, const int* in_sizes, int n_in,
                              void* d_out, int out_size, void* d_ws, size_t ws_size,
                              hipStream_t stream) {
    const float* q     = (const float*)d_in[0];
    const float* gamma = (const float*)d_in[4];
    float* out = (float*)d_out;
    char* ws = (char*)d_ws;
    // ws layout (68.5 MiB; Vt/Vb/KQb are per-half, local-b indexed)
    float* sumV  = (float*)(ws);                     // 32 KiB (16 batches)
    float* cvec  = (float*)(ws + 65536);             // 32 KiB
    float* invn  = (float*)(ws + 98304);             // 32 KiB
    float* dvec  = (float*)(ws + 131072);            // 256 KiB (16 batches)
    unsigned short* KQb = (unsigned short*)(ws + 524288);               // 4 MiB
    unsigned short* Vt  = (unsigned short*)(ws + 524288 + 4194304);     // 32 MiB
    unsigned short* Vb  = (unsigned short*)(ws + 524288 + 4194304 + 33554432); // 32 MiB
    // scratch in upper half of d_out (written+consumed before k6 of half 1 overwrites):
    //   Gp bf16 partials: floats [16777216 .. 16777216+5242880) = 64..84 MiB
    //   ps/pq stat partials: 84..86 MiB
    unsigned short* Gp = (unsigned short*)((float*)d_out + 16777216);   // 20 MiB
    float* ps = (float*)d_out + 22020096;            // 1 MiB (64*4096 floats)
    float* pq = ps + 262144;                         // 1 MiB

    for (int h = 0; h < 2; h++) {
        int bofs = h * 8;
        k1_fused <<<4096, 256, 0, stream>>>(q, Vt, Vb, ps, pq, bofs);
        k2_reduce<<<16,   256, 0, stream>>>(ps, pq, sumV, cvec, invn, bofs);
        k3_dvec  <<<1024, 256, 0, stream>>>(Vb, cvec, dvec, bofs);
        k4_gram  <<<640,  256, 0, stream>>>(Vt, Gp);
        k5_reduce<<<80,   256, 0, stream>>>(Gp, invn, KQb, bofs);
        k6_part  <<<1024, 256, 0, stream>>>(KQb, Vb, dvec, sumV, gamma, out, bofs);
    }
}

// Round 4
// 210.509 us; speedup vs baseline: 1.3802x; 1.1174x over previous
//
#include <hip/hip_runtime.h>

#define EPS 1e-6f
#define LL 4096
#define HE 512

typedef __attribute__((ext_vector_type(8))) short short8;
typedef __attribute__((ext_vector_type(4))) float f32x4;

__device__ __forceinline__ unsigned short f2bf(float f) {
    union { float f; unsigned u; } v; v.f = f;
    unsigned r = v.u + 0x7FFFu + ((v.u >> 16) & 1u);  // RNE
    return (unsigned short)(r >> 16);
}
__device__ __forceinline__ float bf2f(unsigned short s) {
    union { unsigned u; float f; } v; v.u = ((unsigned)s) << 16;
    return v.f;
}
// async global->LDS, 16B per lane; LDS dest = wave-uniform base + lane*16
__device__ __forceinline__ void gl16(const unsigned short* g, unsigned short* l) {
    __builtin_amdgcn_global_load_lds(
        (const __attribute__((address_space(1))) unsigned int*)(const void*)g,
        (__attribute__((address_space(3))) unsigned int*)(void*)l,
        16, 0, 0);
}

// ---- k1: read q once -> Vt (bf16 [n][l]), Vb (bf16 [l][n]), stat partials ----
__global__ __launch_bounds__(256) void k1_fused(const float* __restrict__ q,
        unsigned short* __restrict__ Vt, unsigned short* __restrict__ Vb,
        float* __restrict__ ps, float* __restrict__ pq, int bofs, int pstride) {
    __shared__ unsigned short lds[64][65];
    int blk = blockIdx.x;
    int b = blk >> 9, lt = (blk >> 3) & 63, nt = blk & 7;
    int gb = bofs + b;
    int t = threadIdx.x;
    int row = t >> 4, col = (t & 15) << 2;
    const float* base = q + ((size_t)gb * LL + lt * 64) * HE + nt * 64;
    unsigned short* vbb = Vb + ((size_t)b * LL + lt * 64) * HE + nt * 64;
    #pragma unroll
    for (int i = 0; i < 4; i++) {
        int l = row + i * 16;
        float4 v = *(const float4*)(base + (size_t)l * HE + col);
        ushort4 w;
        w.x = f2bf(v.x); w.y = f2bf(v.y); w.z = f2bf(v.z); w.w = f2bf(v.w);
        lds[col+0][l] = w.x; lds[col+1][l] = w.y;
        lds[col+2][l] = w.z; lds[col+3][l] = w.w;
        *(ushort4*)(vbb + (size_t)l * HE + col) = w;
    }
    __syncthreads();
    unsigned short* ob = Vt + ((size_t)b * HE + nt * 64) * LL + lt * 64;
    #pragma unroll
    for (int i = 0; i < 4; i++) {
        int n = row + i * 16;
        ushort4 w;
        w.x = lds[n][col+0]; w.y = lds[n][col+1];
        w.z = lds[n][col+2]; w.w = lds[n][col+3];
        *(ushort4*)(ob + (size_t)n * LL + col) = w;
        float x0 = bf2f(w.x), x1 = bf2f(w.y), x2 = bf2f(w.z), x3 = bf2f(w.w);
        float s = x0 + x1 + x2 + x3;
        float qq = x0*x0 + x1*x1 + x2*x2 + x3*x3;
        s += __shfl_xor(s, 1);  qq += __shfl_xor(qq, 1);
        s += __shfl_xor(s, 2);  qq += __shfl_xor(qq, 2);
        s += __shfl_xor(s, 4);  qq += __shfl_xor(qq, 4);
        s += __shfl_xor(s, 8);  qq += __shfl_xor(qq, 8);
        if ((t & 15) == 0) {
            int idx = lt * pstride + b * 512 + nt * 64 + n;
            ps[idx] = s;
            pq[idx] = qq;
        }
    }
}

// ---- k2: reduce partials -> sumV, cvec, invn ----------------------------
__global__ __launch_bounds__(256) void k2_reduce(const float* __restrict__ ps,
        const float* __restrict__ pq, float* __restrict__ sumV,
        float* __restrict__ cvec, float* __restrict__ invn, int bofs, int pstride) {
    int i = blockIdx.x * 256 + threadIdx.x;   // 0..pstride-1 = b_local*512 + n
    float s = 0.f, qq = 0.f;
    #pragma unroll 8
    for (int lt = 0; lt < 64; lt++) {
        s  += ps[(size_t)lt * pstride + i];
        qq += pq[(size_t)lt * pstride + i];
    }
    int o = bofs * HE + i;
    float inv = 1.0f / sqrtf(qq);
    sumV[o] = s;
    invn[o] = inv;
    cvec[o] = (s * inv + EPS) * inv;
}

// ---- k3: dvec[b,l] = sum_n Vb[l,n]*cvec[n]  (GEMV) ----------------------
__global__ __launch_bounds__(256) void k3_dvec(const unsigned short* __restrict__ Vb,
        const float* __restrict__ cvec, float* __restrict__ dvec, int bofs) {
    int blk = blockIdx.x;
    int b = blk >> 7, lblk = blk & 127;
    int t = threadIdx.x;
    int lloc = t >> 3, j = t & 7;
    int l = lblk * 32 + lloc;
    const unsigned short* rowp = Vb + ((size_t)b * LL + l) * HE + j * 64;
    const float* cp = cvec + (bofs + b) * HE + j * 64;
    float d = 0.f;
    #pragma unroll
    for (int g = 0; g < 8; g++) {
        short8 v = *(const short8*)(rowp + g * 8);
        float4 c0 = *(const float4*)(cp + g * 8);
        float4 c1 = *(const float4*)(cp + g * 8 + 4);
        d += bf2f((unsigned short)v[0]) * c0.x + bf2f((unsigned short)v[1]) * c0.y
           + bf2f((unsigned short)v[2]) * c0.z + bf2f((unsigned short)v[3]) * c0.w
           + bf2f((unsigned short)v[4]) * c1.x + bf2f((unsigned short)v[5]) * c1.y
           + bf2f((unsigned short)v[6]) * c1.z + bf2f((unsigned short)v[7]) * c1.w;
    }
    d += __shfl_xor(d, 1); d += __shfl_xor(d, 2); d += __shfl_xor(d, 4);
    if (j == 0) dvec[(size_t)(bofs + b) * LL + l] = d;
}

// ---- k4: Gram partials (bf16, [ml][nl]), split-K=8, symmetric pairs -----
__global__ __launch_bounds__(256) void k4_gram(const unsigned short* __restrict__ Vt,
        unsigned short* __restrict__ Gp) {
    __shared__ __attribute__((aligned(16))) unsigned short la[128][64];
    __shared__ __attribute__((aligned(16))) unsigned short lb[128][64];
    int cpx = gridDim.x >> 3;
    int blk = ((int)blockIdx.x & 7) * cpx + ((int)blockIdx.x >> 3);  // XCD swizzle
    int b = blk / 80;
    int rem = blk - b * 80;
    int pair = rem >> 3, split = rem & 7;
    int nt = (pair < 4) ? 0 : (pair < 7) ? 1 : (pair < 9) ? 2 : 3;
    int off = (nt * (9 - nt)) >> 1;
    int mt = nt + pair - off;
    bool diag = (nt == mt);
    int N0 = nt * 128, M0 = mt * 128;
    int t = threadIdx.x;
    int w = t >> 6, lane = t & 63;
    int wr = w >> 1, wc = w & 1;
    int rl = lane >> 3;                    // row-in-8 for staging
    int cl = ((lane & 7) ^ rl) << 3;       // pre-swizzled source chunk (elems)
    int lr = lane & 15, q4 = lane >> 4;
    int ch0 = (q4 ^ (lane & 7)) << 3;      // swizzled read col, ks=0 (elems)
    const unsigned short* pa = Vt + ((size_t)b * HE + N0) * LL + split * 512;
    const unsigned short* pb = Vt + ((size_t)b * HE + M0) * LL + split * 512;
    const unsigned short (*LB)[64] = diag ? la : lb;
    f32x4 acc[4][4] = {};
    for (int kb = 0; kb < 8; kb++) {
        int k0 = kb * 64;
        #pragma unroll
        for (int p = 0; p < 4; p++) {
            int r0 = p * 32 + w * 8;
            gl16(pa + (size_t)(r0 + rl) * LL + k0 + cl, &la[r0][0]);
            if (!diag) gl16(pb + (size_t)(r0 + rl) * LL + k0 + cl, &lb[r0][0]);
        }
        __syncthreads();
        #pragma unroll
        for (int ks = 0; ks < 2; ks++) {
            int colA = ch0 ^ (ks << 5);
            short8 af[4], bfr[4];
            #pragma unroll
            for (int i = 0; i < 4; i++)
                af[i] = *(const short8*)&la[wr*64 + i*16 + lr][colA];
            #pragma unroll
            for (int j = 0; j < 4; j++)
                bfr[j] = *(const short8*)&LB[wc*64 + j*16 + lr][colA];
            #pragma unroll
            for (int i = 0; i < 4; i++)
                #pragma unroll
                for (int j = 0; j < 4; j++)
                    acc[i][j] = __builtin_amdgcn_mfma_f32_16x16x32_bf16(af[i], bfr[j], acc[i][j], 0, 0, 0);
        }
        __syncthreads();
    }
    // store bf16 partials, layout [ml*128 + nl] -> ushort4 along n
    size_t tbase = ((size_t)(b * 10 + pair) * 8 + split) * 16384;
    #pragma unroll
    for (int i = 0; i < 4; i++) {
        int nb = wr*64 + i*16 + q4*4;
        #pragma unroll
        for (int j = 0; j < 4; j++) {
            int ml = wc*64 + j*16 + lr;
            ushort4 wv;
            wv.x = f2bf(acc[i][j][0]); wv.y = f2bf(acc[i][j][1]);
            wv.z = f2bf(acc[i][j][2]); wv.w = f2bf(acc[i][j][3]);
            *(ushort4*)&Gp[tbase + (size_t)ml * 128 + nb] = wv;
        }
    }
}

// ---- k5: sum splits, scale by invn outer, write KQb both orientations ---
__global__ __launch_bounds__(256) void k5_reduce(const unsigned short* __restrict__ Gp,
        const float* __restrict__ invn, unsigned short* __restrict__ KQb, int bofs) {
    __shared__ unsigned short lds_t[128][130];
    int blk = blockIdx.x;
    int b = blk / 10, pair = blk % 10;
    int nt = (pair < 4) ? 0 : (pair < 7) ? 1 : (pair < 9) ? 2 : 3;
    int off = (nt * (9 - nt)) >> 1;
    int mt = nt + pair - off;
    int N0 = nt * 128, M0 = mt * 128;
    int t = threadIdx.x;
    const unsigned short* gp = Gp + ((size_t)(b * 10 + pair) * 8) * 16384;
    const float* inb = invn + (size_t)(bofs + b) * HE;
    #pragma unroll 2
    for (int e = 0; e < 32; e++) {
        int idx = e * 512 + t * 2;           // [ml][nl] pairs
        int ml = idx >> 7, nl = idx & 127;
        float s0 = 0.f, s1 = 0.f;
        #pragma unroll
        for (int sp = 0; sp < 8; sp++) {
            unsigned g2 = *(const unsigned*)&gp[(size_t)sp * 16384 + idx];
            s0 += bf2f((unsigned short)(g2 & 0xFFFF));
            s1 += bf2f((unsigned short)(g2 >> 16));
        }
        float im = inb[M0 + ml];
        ushort2 v;
        v.x = f2bf(s0 * inb[N0 + nl] * im);
        v.y = f2bf(s1 * inb[N0 + nl + 1] * im);
        *(ushort2*)&KQb[((size_t)b * HE + M0 + ml) * HE + N0 + nl] = v;
        *(ushort2*)&lds_t[ml][nl] = v;
    }
    __syncthreads();
    #pragma unroll 2
    for (int e = 0; e < 32; e++) {
        int idx = e * 512 + t * 2;
        int nl = idx >> 7, ml = idx & 127;   // transposed roles
        ushort2 v;
        v.x = lds_t[ml][nl];
        v.y = lds_t[ml + 1][nl];
        *(ushort2*)&KQb[((size_t)b * HE + N0 + nl) * HE + M0 + ml] = v;
    }
}

// ---- k6: part GEMM (KQb x Vb) + tailor/sumV/residual epilogue -----------
__global__ __launch_bounds__(256) void k6_part(const unsigned short* __restrict__ KQb,
        const unsigned short* __restrict__ Vb, const float* __restrict__ dvec,
        const float* __restrict__ sumV, const float* __restrict__ gamma,
        float* __restrict__ out, int bofs) {
    __shared__ __attribute__((aligned(16))) unsigned short la[128][64];
    __shared__ __attribute__((aligned(16))) unsigned short lb[128][64];
    int cpx = gridDim.x >> 3;
    int blk = ((int)blockIdx.x & 7) * cpx + ((int)blockIdx.x >> 3);  // XCD swizzle
    int b = blk >> 7, mt = (blk >> 5) & 3, lt = blk & 31;
    int gb = bofs + b;
    int M0 = mt * 128, L0 = lt * 128;
    int t = threadIdx.x;
    int w = t >> 6, lane = t & 63;
    int wr = w >> 1, wc = w & 1;
    int rl = lane >> 3;
    int cl = ((lane & 7) ^ rl) << 3;
    int lr = lane & 15, q4 = lane >> 4;
    int ch0 = (q4 ^ (lane & 7)) << 3;
    const unsigned short* pa = KQb + ((size_t)b * HE + M0) * HE;
    const unsigned short* pb = Vb + ((size_t)b * LL + L0) * HE;
    f32x4 acc[4][4] = {};
    for (int kb = 0; kb < 8; kb++) {
        int k0 = kb * 64;
        #pragma unroll
        for (int p = 0; p < 4; p++) {
            int r0 = p * 32 + w * 8;
            gl16(pa + (size_t)(r0 + rl) * HE + k0 + cl, &la[r0][0]);
            gl16(pb + (size_t)(r0 + rl) * HE + k0 + cl, &lb[r0][0]);
        }
        __syncthreads();
        #pragma unroll
        for (int ks = 0; ks < 2; ks++) {
            int colA = ch0 ^ (ks << 5);
            short8 af[4], bfr[4];
            #pragma unroll
            for (int i = 0; i < 4; i++)
                af[i] = *(const short8*)&la[wr*64 + i*16 + lr][colA];
            #pragma unroll
            for (int j = 0; j < 4; j++)
                bfr[j] = *(const short8*)&lb[wc*64 + j*16 + lr][colA];
            #pragma unroll
            for (int i = 0; i < 4; i++)
                #pragma unroll
                for (int j = 0; j < 4; j++)
                    acc[i][j] = __builtin_amdgcn_mfma_f32_16x16x32_bf16(af[i], bfr[j], acc[i][j], 0, 0, 0);
        }
        __syncthreads();
    }
    float gma = gamma[0];
    #pragma unroll
    for (int j = 0; j < 4; j++) {
        int lglob = L0 + wc*64 + j*16 + lr;
        float dt = dvec[(size_t)gb * LL + lglob];
        float tailor = 1.0f / (512.0f + dt);
        #pragma unroll
        for (int i = 0; i < 4; i++) {
            int m4 = M0 + wr*64 + i*16 + q4*4;
            size_t ofs = ((size_t)gb * LL + lglob) * HE + m4;
            ushort4 rv = *(const ushort4*)(Vb + ((size_t)b * LL + lglob) * HE + m4);
            float4 vs = *(const float4*)(sumV + (size_t)gb * HE + m4);
            float4 o;
            o.x = bf2f(rv.x) + gma * (vs.x + acc[i][j][0]) * tailor;
            o.y = bf2f(rv.y) + gma * (vs.y + acc[i][j][1]) * tailor;
            o.z = bf2f(rv.z) + gma * (vs.z + acc[i][j][2]) * tailor;
            o.w = bf2f(rv.w) + gma * (vs.w + acc[i][j][3]) * tailor;
            *(float4*)(out + ofs) = o;
        }
    }
}

extern "C" void kernel_launch(void* const* d_in, const int* in_sizes, int n_in,
                              void* d_out, int out_size, void* d_ws, size_t ws_size,
                              hipStream_t stream) {
    const float* q     = (const float*)d_in[0];
    const float* gamma = (const float*)d_in[4];
    float* out = (float*)d_out;
    char* ws = (char*)d_ws;
    // common small buffers
    float* sumV  = (float*)(ws);                     // 32 KiB (16 batches)
    float* cvec  = (float*)(ws + 65536);             // 32 KiB
    float* invn  = (float*)(ws + 98304);             // 32 KiB
    float* dvec  = (float*)(ws + 131072);            // 256 KiB (16 batches)

    if (ws_size >= 190000000ull) {
        // ---------- single pass over all 16 batches, all scratch in ws ----------
        unsigned short* KQb = (unsigned short*)(ws + 524288);        // 8 MiB
        unsigned short* Vt  = (unsigned short*)(ws + 8912896);       // 64 MiB
        unsigned short* Vb  = (unsigned short*)(ws + 76021760);      // 64 MiB
        unsigned short* Gp  = (unsigned short*)(ws + 143130624);     // 40 MiB
        float* ps = (float*)(ws + 185073664);                        // 2 MiB
        float* pq = (float*)(ws + 187170816);                        // 2 MiB
        k1_fused <<<8192, 256, 0, stream>>>(q, Vt, Vb, ps, pq, 0, 8192);
        k2_reduce<<<32,   256, 0, stream>>>(ps, pq, sumV, cvec, invn, 0, 8192);
        k3_dvec  <<<2048, 256, 0, stream>>>(Vb, cvec, dvec, 0);
        k4_gram  <<<1280, 256, 0, stream>>>(Vt, Gp);
        k5_reduce<<<160,  256, 0, stream>>>(Gp, invn, KQb, 0);
        k6_part  <<<2048, 256, 0, stream>>>(KQb, Vb, dvec, sumV, gamma, out, 0);
    } else {
        // ---------- fallback: two-half pipeline, GEMM scratch in d_out tail ----
        unsigned short* KQb = (unsigned short*)(ws + 524288);               // 4 MiB
        unsigned short* Vt  = (unsigned short*)(ws + 524288 + 4194304);     // 32 MiB
        unsigned short* Vb  = (unsigned short*)(ws + 524288 + 4194304 + 33554432); // 32 MiB
        unsigned short* Gp = (unsigned short*)((float*)d_out + 16777216);   // 20 MiB
        float* ps = (float*)d_out + 22020096;            // 1 MiB
        float* pq = ps + 262144;                         // 1 MiB
        for (int h = 0; h < 2; h++) {
            int bofs = h * 8;
            k1_fused <<<4096, 256, 0, stream>>>(q, Vt, Vb, ps, pq, bofs, 4096);
            k2_reduce<<<16,   256, 0, stream>>>(ps, pq, sumV, cvec, invn, bofs, 4096);
            k3_dvec  <<<1024, 256, 0, stream>>>(Vb, cvec, dvec, bofs);
            k4_gram  <<<640,  256, 0, stream>>>(Vt, Gp);
            k5_reduce<<<80,   256, 0, stream>>>(Gp, invn, KQb, bofs);
            k6_part  <<<1024, 256, 0, stream>>>(KQb, Vb, dvec, sumV, gamma, out, bofs);
        }
    }
}

// Round 5
// 199.527 us; speedup vs baseline: 1.4562x; 1.0550x over previous
//
#include <hip/hip_runtime.h>

#define EPS 1e-6f
#define LL 4096
#define HE 512

typedef __attribute__((ext_vector_type(8))) short short8;
typedef __attribute__((ext_vector_type(4))) float f32x4;

__device__ __forceinline__ unsigned short f2bf(float f) {
    union { float f; unsigned u; } v; v.f = f;
    unsigned r = v.u + 0x7FFFu + ((v.u >> 16) & 1u);  // RNE
    return (unsigned short)(r >> 16);
}
__device__ __forceinline__ float bf2f(unsigned short s) {
    union { unsigned u; float f; } v; v.u = ((unsigned)s) << 16;
    return v.f;
}
// async global->LDS, 16B per lane; LDS dest = wave-uniform base + lane*16
__device__ __forceinline__ void gl16(const unsigned short* g, unsigned short* l) {
    __builtin_amdgcn_global_load_lds(
        (const __attribute__((address_space(1))) unsigned int*)(const void*)g,
        (__attribute__((address_space(3))) unsigned int*)(void*)l,
        16, 0, 0);
}

// ---- k1: read q once -> Vt (bf16 [n][l]), Vb (bf16 [l][n]), stat partials ----
__global__ __launch_bounds__(256) void k1_fused(const float* __restrict__ q,
        unsigned short* __restrict__ Vt, unsigned short* __restrict__ Vb,
        float* __restrict__ ps, float* __restrict__ pq, int bofs, int pstride) {
    __shared__ unsigned short lds[64][65];
    int blk = blockIdx.x;
    int b = blk >> 9, lt = (blk >> 3) & 63, nt = blk & 7;
    int gb = bofs + b;
    int t = threadIdx.x;
    int row = t >> 4, col = (t & 15) << 2;
    const float* base = q + ((size_t)gb * LL + lt * 64) * HE + nt * 64;
    unsigned short* vbb = Vb + ((size_t)b * LL + lt * 64) * HE + nt * 64;
    #pragma unroll
    for (int i = 0; i < 4; i++) {
        int l = row + i * 16;
        float4 v = *(const float4*)(base + (size_t)l * HE + col);
        ushort4 w;
        w.x = f2bf(v.x); w.y = f2bf(v.y); w.z = f2bf(v.z); w.w = f2bf(v.w);
        lds[col+0][l] = w.x; lds[col+1][l] = w.y;
        lds[col+2][l] = w.z; lds[col+3][l] = w.w;
        *(ushort4*)(vbb + (size_t)l * HE + col) = w;
    }
    __syncthreads();
    unsigned short* ob = Vt + ((size_t)b * HE + nt * 64) * LL + lt * 64;
    #pragma unroll
    for (int i = 0; i < 4; i++) {
        int n = row + i * 16;
        ushort4 w;
        w.x = lds[n][col+0]; w.y = lds[n][col+1];
        w.z = lds[n][col+2]; w.w = lds[n][col+3];
        *(ushort4*)(ob + (size_t)n * LL + col) = w;
        float x0 = bf2f(w.x), x1 = bf2f(w.y), x2 = bf2f(w.z), x3 = bf2f(w.w);
        float s = x0 + x1 + x2 + x3;
        float qq = x0*x0 + x1*x1 + x2*x2 + x3*x3;
        s += __shfl_xor(s, 1);  qq += __shfl_xor(qq, 1);
        s += __shfl_xor(s, 2);  qq += __shfl_xor(qq, 2);
        s += __shfl_xor(s, 4);  qq += __shfl_xor(qq, 4);
        s += __shfl_xor(s, 8);  qq += __shfl_xor(qq, 8);
        if ((t & 15) == 0) {
            int idx = lt * pstride + b * 512 + nt * 64 + n;
            ps[idx] = s;
            pq[idx] = qq;
        }
    }
}

// ---- k2: reduce partials -> sumV, cvec, invn ----------------------------
__global__ __launch_bounds__(256) void k2_reduce(const float* __restrict__ ps,
        const float* __restrict__ pq, float* __restrict__ sumV,
        float* __restrict__ cvec, float* __restrict__ invn, int bofs, int pstride) {
    int i = blockIdx.x * 256 + threadIdx.x;   // 0..pstride-1 = b_local*512 + n
    float s = 0.f, qq = 0.f;
    #pragma unroll 8
    for (int lt = 0; lt < 64; lt++) {
        s  += ps[(size_t)lt * pstride + i];
        qq += pq[(size_t)lt * pstride + i];
    }
    int o = bofs * HE + i;
    float inv = 1.0f / sqrtf(qq);
    sumV[o] = s;
    invn[o] = inv;
    cvec[o] = (s * inv + EPS) * inv;
}

// ---- k3: dvec[b,l] = sum_n Vb[l,n]*cvec[n]  (GEMV) ----------------------
__global__ __launch_bounds__(256) void k3_dvec(const unsigned short* __restrict__ Vb,
        const float* __restrict__ cvec, float* __restrict__ dvec, int bofs) {
    int blk = blockIdx.x;
    int b = blk >> 7, lblk = blk & 127;
    int t = threadIdx.x;
    int lloc = t >> 3, j = t & 7;
    int l = lblk * 32 + lloc;
    const unsigned short* rowp = Vb + ((size_t)b * LL + l) * HE + j * 64;
    const float* cp = cvec + (bofs + b) * HE + j * 64;
    float d = 0.f;
    #pragma unroll
    for (int g = 0; g < 8; g++) {
        short8 v = *(const short8*)(rowp + g * 8);
        float4 c0 = *(const float4*)(cp + g * 8);
        float4 c1 = *(const float4*)(cp + g * 8 + 4);
        d += bf2f((unsigned short)v[0]) * c0.x + bf2f((unsigned short)v[1]) * c0.y
           + bf2f((unsigned short)v[2]) * c0.z + bf2f((unsigned short)v[3]) * c0.w
           + bf2f((unsigned short)v[4]) * c1.x + bf2f((unsigned short)v[5]) * c1.y
           + bf2f((unsigned short)v[6]) * c1.z + bf2f((unsigned short)v[7]) * c1.w;
    }
    d += __shfl_xor(d, 1); d += __shfl_xor(d, 2); d += __shfl_xor(d, 4);
    if (j == 0) dvec[(size_t)(bofs + b) * LL + l] = d;
}

// ---- k4: Gram partials (bf16, [ml][nl]), split-K=8, symmetric pairs -----
// 2-phase double-buffered: counted vmcnt + raw s_barrier (T3 minimum recipe)
__global__ __launch_bounds__(256) void k4_gram(const unsigned short* __restrict__ Vt,
        unsigned short* __restrict__ Gp) {
    __shared__ __attribute__((aligned(16))) unsigned short la[2][128][64];
    __shared__ __attribute__((aligned(16))) unsigned short lb[2][128][64];
    int cpx = gridDim.x >> 3;
    int blk = ((int)blockIdx.x & 7) * cpx + ((int)blockIdx.x >> 3);  // XCD swizzle
    int b = blk / 80;
    int rem = blk - b * 80;
    int pair = rem >> 3, split = rem & 7;
    int nt = (pair < 4) ? 0 : (pair < 7) ? 1 : (pair < 9) ? 2 : 3;
    int off = (nt * (9 - nt)) >> 1;
    int mt = nt + pair - off;
    bool diag = (nt == mt);
    int N0 = nt * 128, M0 = mt * 128;
    int t = threadIdx.x;
    int w = t >> 6, lane = t & 63;
    int wr = w >> 1, wc = w & 1;
    int rl = lane >> 3;                    // row-in-8 for staging
    int cl = ((lane & 7) ^ rl) << 3;       // pre-swizzled source chunk (elems)
    int lr = lane & 15, q4 = lane >> 4;
    int ch0 = (q4 ^ (lane & 7)) << 3;      // swizzled read col, ks=0 (elems)
    const unsigned short* pa = Vt + ((size_t)b * HE + N0) * LL + split * 512;
    const unsigned short* pb = Vt + ((size_t)b * HE + M0) * LL + split * 512;
    f32x4 acc[4][4] = {};

#define STAGE4(B, KB) do { \
    int _k0 = (KB) * 64; \
    _Pragma("unroll") \
    for (int p = 0; p < 4; p++) { \
        int r0 = p * 32 + w * 8; \
        gl16(pa + (size_t)(r0 + rl) * LL + _k0 + cl, &la[B][r0][0]); \
        if (!diag) gl16(pb + (size_t)(r0 + rl) * LL + _k0 + cl, &lb[B][r0][0]); \
    } } while (0)

    STAGE4(0, 0);  // prologue
    #pragma unroll
    for (int kb = 0; kb < 8; kb++) {
        int cur = kb & 1;
        if (kb < 7) {
            STAGE4(cur ^ 1, kb + 1);
            if (diag) { asm volatile("s_waitcnt vmcnt(4)" ::: "memory"); }
            else      { asm volatile("s_waitcnt vmcnt(8)" ::: "memory"); }
        } else {
            asm volatile("s_waitcnt vmcnt(0)" ::: "memory");
        }
        __builtin_amdgcn_s_barrier();
        const unsigned short (*A)[64] = la[cur];
        const unsigned short (*Bp)[64] = diag ? la[cur] : lb[cur];
        #pragma unroll
        for (int ks = 0; ks < 2; ks++) {
            int colA = ch0 ^ (ks << 5);
            short8 af[4], bfr[4];
            #pragma unroll
            for (int i = 0; i < 4; i++)
                af[i] = *(const short8*)&A[wr*64 + i*16 + lr][colA];
            #pragma unroll
            for (int j = 0; j < 4; j++)
                bfr[j] = *(const short8*)&Bp[wc*64 + j*16 + lr][colA];
            #pragma unroll
            for (int i = 0; i < 4; i++)
                #pragma unroll
                for (int j = 0; j < 4; j++)
                    acc[i][j] = __builtin_amdgcn_mfma_f32_16x16x32_bf16(af[i], bfr[j], acc[i][j], 0, 0, 0);
        }
        __builtin_amdgcn_s_barrier();
    }
#undef STAGE4
    // store bf16 partials, layout [ml*128 + nl] -> ushort4 along n
    size_t tbase = ((size_t)(b * 10 + pair) * 8 + split) * 16384;
    #pragma unroll
    for (int i = 0; i < 4; i++) {
        int nb = wr*64 + i*16 + q4*4;
        #pragma unroll
        for (int j = 0; j < 4; j++) {
            int ml = wc*64 + j*16 + lr;
            ushort4 wv;
            wv.x = f2bf(acc[i][j][0]); wv.y = f2bf(acc[i][j][1]);
            wv.z = f2bf(acc[i][j][2]); wv.w = f2bf(acc[i][j][3]);
            *(ushort4*)&Gp[tbase + (size_t)ml * 128 + nb] = wv;
        }
    }
}

// ---- k5: sum splits, scale by invn outer, write KQb both orientations ---
__global__ __launch_bounds__(256) void k5_reduce(const unsigned short* __restrict__ Gp,
        const float* __restrict__ invn, unsigned short* __restrict__ KQb, int bofs) {
    __shared__ unsigned short lds_t[128][130];
    int blk = blockIdx.x;
    int b = blk / 10, pair = blk % 10;
    int nt = (pair < 4) ? 0 : (pair < 7) ? 1 : (pair < 9) ? 2 : 3;
    int off = (nt * (9 - nt)) >> 1;
    int mt = nt + pair - off;
    int N0 = nt * 128, M0 = mt * 128;
    int t = threadIdx.x;
    const unsigned short* gp = Gp + ((size_t)(b * 10 + pair) * 8) * 16384;
    const float* inb = invn + (size_t)(bofs + b) * HE;
    #pragma unroll 2
    for (int e = 0; e < 32; e++) {
        int idx = e * 512 + t * 2;           // [ml][nl] pairs
        int ml = idx >> 7, nl = idx & 127;
        float s0 = 0.f, s1 = 0.f;
        #pragma unroll
        for (int sp = 0; sp < 8; sp++) {
            unsigned g2 = *(const unsigned*)&gp[(size_t)sp * 16384 + idx];
            s0 += bf2f((unsigned short)(g2 & 0xFFFF));
            s1 += bf2f((unsigned short)(g2 >> 16));
        }
        float im = inb[M0 + ml];
        ushort2 v;
        v.x = f2bf(s0 * inb[N0 + nl] * im);
        v.y = f2bf(s1 * inb[N0 + nl + 1] * im);
        *(ushort2*)&KQb[((size_t)b * HE + M0 + ml) * HE + N0 + nl] = v;
        *(ushort2*)&lds_t[ml][nl] = v;
    }
    __syncthreads();
    #pragma unroll 2
    for (int e = 0; e < 32; e++) {
        int idx = e * 512 + t * 2;
        int nl = idx >> 7, ml = idx & 127;   // transposed roles
        ushort2 v;
        v.x = lds_t[ml][nl];
        v.y = lds_t[ml + 1][nl];
        *(ushort2*)&KQb[((size_t)b * HE + N0 + nl) * HE + M0 + ml] = v;
    }
}

// ---- k6: part GEMM (KQb x Vb) + tailor/sumV/residual epilogue -----------
// 2-phase double-buffered: counted vmcnt + raw s_barrier (T3 minimum recipe)
__global__ __launch_bounds__(256) void k6_part(const unsigned short* __restrict__ KQb,
        const unsigned short* __restrict__ Vb, const float* __restrict__ dvec,
        const float* __restrict__ sumV, const float* __restrict__ gamma,
        float* __restrict__ out, int bofs) {
    __shared__ __attribute__((aligned(16))) unsigned short la[2][128][64];
    __shared__ __attribute__((aligned(16))) unsigned short lb[2][128][64];
    int cpx = gridDim.x >> 3;
    int blk = ((int)blockIdx.x & 7) * cpx + ((int)blockIdx.x >> 3);  // XCD swizzle
    int b = blk >> 7, mt = (blk >> 5) & 3, lt = blk & 31;
    int gb = bofs + b;
    int M0 = mt * 128, L0 = lt * 128;
    int t = threadIdx.x;
    int w = t >> 6, lane = t & 63;
    int wr = w >> 1, wc = w & 1;
    int rl = lane >> 3;
    int cl = ((lane & 7) ^ rl) << 3;
    int lr = lane & 15, q4 = lane >> 4;
    int ch0 = (q4 ^ (lane & 7)) << 3;
    const unsigned short* pa = KQb + ((size_t)b * HE + M0) * HE;
    const unsigned short* pb = Vb + ((size_t)b * LL + L0) * HE;
    float gma = gamma[0];   // hoisted above prologue so vmcnt counting stays exact
    f32x4 acc[4][4] = {};

#define STAGE6(B, KB) do { \
    int _k0 = (KB) * 64; \
    _Pragma("unroll") \
    for (int p = 0; p < 4; p++) { \
        int r0 = p * 32 + w * 8; \
        gl16(pa + (size_t)(r0 + rl) * HE + _k0 + cl, &la[B][r0][0]); \
        gl16(pb + (size_t)(r0 + rl) * HE + _k0 + cl, &lb[B][r0][0]); \
    } } while (0)

    STAGE6(0, 0);  // prologue
    #pragma unroll
    for (int kb = 0; kb < 8; kb++) {
        int cur = kb & 1;
        if (kb < 7) {
            STAGE6(cur ^ 1, kb + 1);
            asm volatile("s_waitcnt vmcnt(8)" ::: "memory");
        } else {
            asm volatile("s_waitcnt vmcnt(0)" ::: "memory");
        }
        __builtin_amdgcn_s_barrier();
        #pragma unroll
        for (int ks = 0; ks < 2; ks++) {
            int colA = ch0 ^ (ks << 5);
            short8 af[4], bfr[4];
            #pragma unroll
            for (int i = 0; i < 4; i++)
                af[i] = *(const short8*)&la[cur][wr*64 + i*16 + lr][colA];
            #pragma unroll
            for (int j = 0; j < 4; j++)
                bfr[j] = *(const short8*)&lb[cur][wc*64 + j*16 + lr][colA];
            #pragma unroll
            for (int i = 0; i < 4; i++)
                #pragma unroll
                for (int j = 0; j < 4; j++)
                    acc[i][j] = __builtin_amdgcn_mfma_f32_16x16x32_bf16(af[i], bfr[j], acc[i][j], 0, 0, 0);
        }
        __builtin_amdgcn_s_barrier();
    }
#undef STAGE6
    #pragma unroll
    for (int j = 0; j < 4; j++) {
        int lglob = L0 + wc*64 + j*16 + lr;
        float dt = dvec[(size_t)gb * LL + lglob];
        float tailor = 1.0f / (512.0f + dt);
        #pragma unroll
        for (int i = 0; i < 4; i++) {
            int m4 = M0 + wr*64 + i*16 + q4*4;
            size_t ofs = ((size_t)gb * LL + lglob) * HE + m4;
            ushort4 rv = *(const ushort4*)(Vb + ((size_t)b * LL + lglob) * HE + m4);
            float4 vs = *(const float4*)(sumV + (size_t)gb * HE + m4);
            float4 o;
            o.x = bf2f(rv.x) + gma * (vs.x + acc[i][j][0]) * tailor;
            o.y = bf2f(rv.y) + gma * (vs.y + acc[i][j][1]) * tailor;
            o.z = bf2f(rv.z) + gma * (vs.z + acc[i][j][2]) * tailor;
            o.w = bf2f(rv.w) + gma * (vs.w + acc[i][j][3]) * tailor;
            *(float4*)(out + ofs) = o;
        }
    }
}

extern "C" void kernel_launch(void* const* d_in, const int* in_sizes, int n_in,
                              void* d_out, int out_size, void* d_ws, size_t ws_size,
                              hipStream_t stream) {
    const float* q     = (const float*)d_in[0];
    const float* gamma = (const float*)d_in[4];
    float* out = (float*)d_out;
    char* ws = (char*)d_ws;
    // common small buffers
    float* sumV  = (float*)(ws);                     // 32 KiB (16 batches)
    float* cvec  = (float*)(ws + 65536);             // 32 KiB
    float* invn  = (float*)(ws + 98304);             // 32 KiB
    float* dvec  = (float*)(ws + 131072);            // 256 KiB (16 batches)

    if (ws_size >= 190000000ull) {
        // ---------- single pass over all 16 batches, all scratch in ws ----------
        unsigned short* KQb = (unsigned short*)(ws + 524288);        // 8 MiB
        unsigned short* Vt  = (unsigned short*)(ws + 8912896);       // 64 MiB
        unsigned short* Vb  = (unsigned short*)(ws + 76021760);      // 64 MiB
        unsigned short* Gp  = (unsigned short*)(ws + 143130624);     // 40 MiB
        float* ps = (float*)(ws + 185073664);                        // 2 MiB
        float* pq = (float*)(ws + 187170816);                        // 2 MiB
        k1_fused <<<8192, 256, 0, stream>>>(q, Vt, Vb, ps, pq, 0, 8192);
        k2_reduce<<<32,   256, 0, stream>>>(ps, pq, sumV, cvec, invn, 0, 8192);
        k3_dvec  <<<2048, 256, 0, stream>>>(Vb, cvec, dvec, 0);
        k4_gram  <<<1280, 256, 0, stream>>>(Vt, Gp);
        k5_reduce<<<160,  256, 0, stream>>>(Gp, invn, KQb, 0);
        k6_part  <<<2048, 256, 0, stream>>>(KQb, Vb, dvec, sumV, gamma, out, 0);
    } else {
        // ---------- fallback: two-half pipeline, GEMM scratch in d_out tail ----
        unsigned short* KQb = (unsigned short*)(ws + 524288);               // 4 MiB
        unsigned short* Vt  = (unsigned short*)(ws + 524288 + 4194304);     // 32 MiB
        unsigned short* Vb  = (unsigned short*)(ws + 524288 + 4194304 + 33554432); // 32 MiB
        unsigned short* Gp = (unsigned short*)((float*)d_out + 16777216);   // 20 MiB
        float* ps = (float*)d_out + 22020096;            // 1 MiB
        float* pq = ps + 262144;                         // 1 MiB
        for (int h = 0; h < 2; h++) {
            int bofs = h * 8;
            k1_fused <<<4096, 256, 0, stream>>>(q, Vt, Vb, ps, pq, bofs, 4096);
            k2_reduce<<<16,   256, 0, stream>>>(ps, pq, sumV, cvec, invn, bofs, 4096);
            k3_dvec  <<<1024, 256, 0, stream>>>(Vb, cvec, dvec, bofs);
            k4_gram  <<<640,  256, 0, stream>>>(Vt, Gp);
            k5_reduce<<<80,   256, 0, stream>>>(Gp, invn, KQb, bofs);
            k6_part  <<<1024, 256, 0, stream>>>(KQb, Vb, dvec, sumV, gamma, out, bofs);
        }
    }
}